// Round 25
// baseline (81.883 us; speedup 1.0000x reference)
//
#include <hip/hip_runtime.h>
#include <hip/hip_bf16.h>

#define B_ 256
#define N_ 784
#define E_ 6272
#define C_ 32
#define H_ 512
#define NK 25088            // N_*C_  (K of fc1; wf1t row stride)
#define S_SPLIT 56          // split-K factor (ksteps = 7 per chunk)

typedef __attribute__((ext_vector_type(8))) short short8;
typedef __attribute__((ext_vector_type(4))) float f32x4;

__device__ __forceinline__ float elu1(float v) {
  return v > 0.f ? v : (__expf(v) - 1.f);
}

__device__ __forceinline__ unsigned short bf16b(float v) {
  __hip_bfloat16 h = __float2bfloat16(v);
  return *reinterpret_cast<unsigned short*>(&h);
}

__device__ __forceinline__ unsigned int pk2(float lo, float hi) {
  return (unsigned int)bf16b(lo) | ((unsigned int)bf16b(hi) << 16);
}

// ---- K0: block 0 = CSR; blocks 1..200 = x transpose ----
__global__ __launch_bounds__(1024) void k_prep(
    const int* __restrict__ erow, const int* __restrict__ ecol,
    const float* __restrict__ eval, const float* __restrict__ x,
    int* __restrict__ row_ptr, int* __restrict__ col_s, float* __restrict__ val_s,
    float* __restrict__ xT) {
  const int t = threadIdx.x;
  if (blockIdx.x == 0) {
    __shared__ int cnt[N_];
    __shared__ int off[N_];
    __shared__ int bufA[1024];
    __shared__ int bufB[1024];
    if (t < N_) cnt[t] = 0;
    __syncthreads();
    for (int e = t; e < E_; e += 1024) atomicAdd(&cnt[erow[e]], 1);
    __syncthreads();
    bufA[t] = (t < N_) ? cnt[t] : 0;
    __syncthreads();
    int* src = bufA; int* dst = bufB;
    for (int d = 1; d < 1024; d <<= 1) {
      int v = src[t];
      if (t >= d) v += src[t - d];
      dst[t] = v;
      __syncthreads();
      int* tmp = src; src = dst; dst = tmp;
    }
    if (t < N_) {
      int ex = src[t] - cnt[t];
      off[t] = ex;
      row_ptr[t] = ex;
    }
    if (t == 0) row_ptr[N_] = E_;
    __syncthreads();
    for (int e = t; e < E_; e += 1024) {
      int r = erow[e];
      int p = atomicAdd(&off[r], 1);
      col_s[p] = ecol[e];
      val_s[p] = eval[e];
    }
  } else {
    __shared__ float tile[32][33];
    int bid = blockIdx.x - 1;
    int n0 = (bid % 25) * 32, b0 = (bid / 25) * 32;
    int ni = t & 31, bi = t >> 5;
    int n = n0 + ni;
    if (n < N_) tile[ni][bi] = x[(b0 + bi) * N_ + n];
    __syncthreads();
    int nj = t >> 5, bj = t & 31;
    int nw = n0 + nj;
    if (nw < N_) xT[nw * B_ + b0 + bj] = tile[nj][bj];
  }
}

// ---- K1: blocks [0,784): spmm1 -> agg1[n][b] (f32 scalar per node)
//      blocks [784,2352): Wf1 cvt+T part1 (k in [0,12544), 64x64 tiles) ----
__global__ __launch_bounds__(256) void k_gc1(
    const float* __restrict__ xT, const int* __restrict__ row_ptr,
    const int* __restrict__ col_s, const float* __restrict__ val_s,
    const float* __restrict__ Wf1, __hip_bfloat16* __restrict__ wf1t,
    float* __restrict__ agg1) {
  __shared__ union {
    struct { int lc[64]; float lv[64]; } g;
    float tile[64][65];
  } sm;
  int t = threadIdx.x;
  if (blockIdx.x < N_) {
    int n = blockIdx.x;
    int e0 = row_ptr[n], deg = row_ptr[n + 1] - e0;
    float agg = 0.f;
    for (int base = 0; base < deg; base += 64) {
      int m = min(64, deg - base);
      __syncthreads();
      if (t < m) { sm.g.lc[t] = col_s[e0 + base + t]; sm.g.lv[t] = val_s[e0 + base + t]; }
      __syncthreads();
      int e = 0;
      for (; e + 4 <= m; e += 4) {
        float x0 = xT[sm.g.lc[e + 0] * B_ + t];
        float x1 = xT[sm.g.lc[e + 1] * B_ + t];
        float x2 = xT[sm.g.lc[e + 2] * B_ + t];
        float x3 = xT[sm.g.lc[e + 3] * B_ + t];
        agg = fmaf(sm.g.lv[e + 0], x0, agg);
        agg = fmaf(sm.g.lv[e + 1], x1, agg);
        agg = fmaf(sm.g.lv[e + 2], x2, agg);
        agg = fmaf(sm.g.lv[e + 3], x3, agg);
      }
      for (; e < m; ++e)
        agg = fmaf(sm.g.lv[e], xT[sm.g.lc[e] * B_ + t], agg);
    }
    agg1[n * B_ + t] = agg;
  } else {
    // Wf1 transpose part1: 196 k-tiles x 8 n-tiles of 64x64, k0 in [0, 12544)
    int bid = blockIdx.x - N_;                 // 0..1567
    int k0 = (bid % 196) * 64, n0 = (bid / 196) * 64;
#pragma unroll
    for (int it = 0; it < 16; ++it) {
      int idx = it * 256 + t;
      int kk = idx >> 6, nn = idx & 63;
      sm.tile[kk][nn] = Wf1[(size_t)(k0 + kk) * H_ + n0 + nn];
    }
    __syncthreads();
#pragma unroll
    for (int it = 0; it < 8; ++it) {
      int idx = it * 256 + t;
      int nn = idx >> 5, kp = idx & 31;
      unsigned int v = pk2(sm.tile[2 * kp][nn], sm.tile[2 * kp + 1][nn]);
      *reinterpret_cast<unsigned int*>(
          wf1t + (size_t)(n0 + nn) * NK + k0 + 2 * kp) = v;
    }
  }
}

// ---- K2: blocks [0,3136): spmm2 via SCALAR gather + in-register h recompute
//      blocks [3136,9408): Wf1 cvt+T part2 (k in [12544,25088), 32x32 tiles) ----
__global__ __launch_bounds__(64) void k_gc2(
    const float* __restrict__ agg1, const int* __restrict__ row_ptr,
    const int* __restrict__ col_s, const float* __restrict__ val_s,
    const float* __restrict__ W1, const float* __restrict__ b1,
    const float* __restrict__ W2, const float* __restrict__ b2,
    const float* __restrict__ Wf1, __hip_bfloat16* __restrict__ wf1t,
    __hip_bfloat16* __restrict__ flat) {
  __shared__ union {
    struct { int lc[64]; float lv[64]; } g;
    float tile[32][33];
  } sm;
  int bid = blockIdx.x;
  int t = threadIdx.x;
  if (bid < N_ * 4) {
    int q = bid & 3;
    int n = bid >> 2;
    int tb = q * 64 + t;
    int e0 = row_ptr[n], deg = row_ptr[n + 1] - e0;
    float w1r[C_], b1r[C_];
#pragma unroll
    for (int c = 0; c < C_; ++c) { w1r[c] = W1[c]; b1r[c] = b1[c]; }
    float acc[C_];
#pragma unroll
    for (int c = 0; c < C_; ++c) acc[c] = 0.f;
    for (int base = 0; base < deg; base += 64) {
      int m = min(64, deg - base);
      __syncthreads();
      if (t < m) { sm.g.lc[t] = col_s[e0 + base + t]; sm.g.lv[t] = val_s[e0 + base + t]; }
      __syncthreads();
      int e = 0;
      for (; e + 4 <= m; e += 4) {
        float s0 = agg1[sm.g.lc[e + 0] * B_ + tb];
        float s1 = agg1[sm.g.lc[e + 1] * B_ + tb];
        float s2 = agg1[sm.g.lc[e + 2] * B_ + tb];
        float s3 = agg1[sm.g.lc[e + 3] * B_ + tb];
        float v0 = sm.g.lv[e + 0], v1 = sm.g.lv[e + 1];
        float v2 = sm.g.lv[e + 2], v3 = sm.g.lv[e + 3];
#pragma unroll
        for (int c = 0; c < C_; ++c) {
          acc[c] = fmaf(v0, elu1(fmaf(s0, w1r[c], b1r[c])), acc[c]);
          acc[c] = fmaf(v1, elu1(fmaf(s1, w1r[c], b1r[c])), acc[c]);
          acc[c] = fmaf(v2, elu1(fmaf(s2, w1r[c], b1r[c])), acc[c]);
          acc[c] = fmaf(v3, elu1(fmaf(s3, w1r[c], b1r[c])), acc[c]);
        }
      }
      for (; e < m; ++e) {
        float s0 = agg1[sm.g.lc[e] * B_ + tb];
        float v0 = sm.g.lv[e];
#pragma unroll
        for (int c = 0; c < C_; ++c)
          acc[c] = fmaf(v0, elu1(fmaf(s0, w1r[c], b1r[c])), acc[c]);
      }
    }
    union { unsigned int u[16]; uint4 v[4]; } ob;
#pragma unroll
    for (int c2 = 0; c2 < C_; c2 += 2) {
      float o0 = b2[c2], o1 = b2[c2 + 1];
#pragma unroll
      for (int c = 0; c < C_; ++c) {
        o0 = fmaf(acc[c], W2[c * C_ + c2], o0);
        o1 = fmaf(acc[c], W2[c * C_ + c2 + 1], o1);
      }
      ob.u[c2 >> 1] = pk2(elu1(o0), elu1(o1));
    }
    uint4* dst = reinterpret_cast<uint4*>(flat + (size_t)tb * NK + n * C_);
#pragma unroll
    for (int j = 0; j < 4; ++j) dst[j] = ob.v[j];
  } else {
    // Wf1 transpose part2: 392 k-tiles x 16 n-tiles of 32x32, k0 in [12544, NK)
    int bid2 = bid - N_ * 4;                   // 0..6271
    int k0 = 12544 + (bid2 % 392) * 32, n0 = (bid2 / 392) * 32;
#pragma unroll
    for (int it = 0; it < 16; ++it) {
      int idx = it * 64 + t;
      int kk = idx >> 5, nn = idx & 31;
      sm.tile[kk][nn] = Wf1[(size_t)(k0 + kk) * H_ + n0 + nn];
    }
    __syncthreads();
#pragma unroll
    for (int it = 0; it < 8; ++it) {
      int idx = it * 64 + t;
      int nn = idx >> 4, kp = idx & 15;
      unsigned int v = pk2(sm.tile[2 * kp][nn], sm.tile[2 * kp + 1][nn]);
      *reinterpret_cast<unsigned int*>(
          wf1t + (size_t)(n0 + nn) * NK + k0 + 2 * kp) = v;
    }
  }
}

// ---- K3: fc1 split-K MFMA GEMM, BM=128 x BN=128, 8 waves, 2-buffer pipeline ----
// grid = 56 s x 2 mt x 4 nt = 448 (XCD-swizzled); 512 threads = 8 waves (2m x 4n),
// wave tile 64x32, acc[4][2]. 32 x 1KB fragment regions per buffer (A:0-15, B:16-31);
// wave w stages regions w*4..w*4+3. 2 buffers (64KB LDS -> 2 blocks/CU co-resident);
// step: VWAIT(4) -> BAR -> COMPUTE(t) -> BAR -> STAGE(t+2 into freed buffer).
// Correctness: every wave VWAITs its OWN stage(t) loads before the first barrier,
// so after it ALL regions of buffer t%2 are complete; second barrier guarantees all
// waves finished reading t%2 before it is overwritten by stage(t+2).
__global__ __launch_bounds__(512, 2) void k_fc1(
    const __hip_bfloat16* __restrict__ flat, const __hip_bfloat16* __restrict__ wf1t,
    float* __restrict__ partial) {
  __shared__ unsigned char lds[2 * 32768];
  int raw = blockIdx.x;
  int bid = (raw & 7) * 56 + (raw >> 3);      // bijective XCD swizzle (448 = 8*56)
  int s = bid >> 3, r8 = bid & 7;
  int m0 = (r8 & 1) * 128;
  int n0 = (r8 >> 1) * 128;
  int k0 = s * 448;                            // 7 steps x 64
  int tid = threadIdx.x;
  int w = tid >> 6, l = tid & 63;
  int r = l & 15, g = l >> 4;

  // This wave's 4 staging regions (region ids w*4+j of 32).
  const __hip_bfloat16* src[4];
  int ldsoff[4];
#pragma unroll
  for (int j = 0; j < 4; ++j) {
    int reg = w * 4 + j;
    ldsoff[j] = reg * 1024 + l * 16;
    if (reg < 16) {
      int fmg = reg >> 1, ks = reg & 1;
      src[j] = flat + (size_t)(m0 + fmg * 16 + r) * NK + (k0 + ks * 32 + g * 8);
    } else {
      int fng = (reg - 16) >> 1, ks = reg & 1;
      src[j] = wf1t + (size_t)(n0 + fng * 16 + r) * NK + (k0 + ks * 32 + g * 8);
    }
  }

  f32x4 acc[4][2];
#pragma unroll
  for (int i = 0; i < 4; ++i)
#pragma unroll
    for (int j = 0; j < 2; ++j) acc[i][j] = (f32x4){0.f, 0.f, 0.f, 0.f};

#define GLOAD_LDS(gp, lp)                                                     \
  __builtin_amdgcn_global_load_lds(                                           \
      (const __attribute__((address_space(1))) unsigned int*)(gp),            \
      (__attribute__((address_space(3))) unsigned int*)(lp), 16, 0, 0)
#define STAGE(t, buf) do {                                                    \
    _Pragma("unroll")                                                         \
    for (int j = 0; j < 4; ++j)                                               \
      GLOAD_LDS(src[j] + (t) * 64, &lds[(buf) * 32768 + ldsoff[j]]);          \
  } while (0)
#define VWAIT(n) do {                                                         \
    asm volatile("s_waitcnt vmcnt(%0)" :: "n"(n) : "memory");                 \
    __builtin_amdgcn_sched_barrier(0);                                        \
  } while (0)
#define BAR() do {                                                            \
    __builtin_amdgcn_s_barrier();                                             \
    __builtin_amdgcn_sched_barrier(0);                                        \
  } while (0)
#define COMPUTE(buf) do {                                                     \
    const unsigned char* bb = &lds[(buf) * 32768];                            \
    short8 af[4][2], bf[2][2];                                                \
    _Pragma("unroll")                                                         \
    for (int fm = 0; fm < 4; ++fm)                                            \
      _Pragma("unroll")                                                       \
      for (int ks = 0; ks < 2; ++ks)                                          \
        af[fm][ks] = *reinterpret_cast<const short8*>(                        \
            bb + ((((w & 1) * 4 + fm) * 2 + ks) << 10) + l * 16);             \
    _Pragma("unroll")                                                         \
    for (int fn = 0; fn < 2; ++fn)                                            \
      _Pragma("unroll")                                                       \
      for (int ks = 0; ks < 2; ++ks)                                          \
        bf[fn][ks] = *reinterpret_cast<const short8*>(                        \
            bb + ((16 + ((w >> 1) * 2 + fn) * 2 + ks) << 10) + l * 16);       \
    _Pragma("unroll")                                                         \
    for (int ks = 0; ks < 2; ++ks)                                            \
      _Pragma("unroll")                                                       \
      for (int fn = 0; fn < 2; ++fn)                                          \
        _Pragma("unroll")                                                     \
        for (int fm = 0; fm < 4; ++fm)                                        \
          acc[fm][fn] = __builtin_amdgcn_mfma_f32_16x16x32_bf16(              \
              af[fm][ks], bf[fn][ks], acc[fm][fn], 0, 0, 0);                  \
  } while (0)
#define STEP(t) do {                                                          \
    VWAIT((t) < 6 ? 4 : 0);                                                   \
    BAR();                                                                    \
    COMPUTE((t) & 1);                                                         \
    BAR();                                                                    \
    if ((t) + 2 <= 6) STAGE((t) + 2, (t) & 1);                                \
  } while (0)

  STAGE(0, 0);
  STAGE(1, 1);
  STEP(0);  STEP(1);  STEP(2);  STEP(3);  STEP(4);  STEP(5);  STEP(6);

#undef GLOAD_LDS
#undef STAGE
#undef VWAIT
#undef BAR
#undef COMPUTE
#undef STEP

  int wm = (w & 1) * 64, wn = (w >> 1) * 32;
  float* p = partial + (size_t)s * (256 * 512);
#pragma unroll
  for (int fm = 0; fm < 4; ++fm)
#pragma unroll
    for (int fn = 0; fn < 2; ++fn)
#pragma unroll
      for (int q = 0; q < 4; ++q) {
        int m = m0 + wm + fm * 16 + g * 4 + q;
        int n = n0 + wn + fn * 16 + r;
        p[m * 512 + n] = acc[fm][fn][q];
      }
}

// ---------------- K4: reduce partials + bias + relu + fc2 + softmax ----------------
__global__ __launch_bounds__(512) void k_head(
    const float* __restrict__ partial, const float* __restrict__ bf1,
    const float* __restrict__ Wf2, const float* __restrict__ bf2,
    float* __restrict__ out) {
  __shared__ float red[8][12];
  int b = blockIdx.x;
  int t = threadIdx.x;
  float v = bf1[t];
#pragma unroll
  for (int s = 0; s < S_SPLIT; ++s)
    v += partial[(size_t)s * (256 * 512) + b * 512 + t];
  v = fmaxf(v, 0.f);
  float pacc[10];
#pragma unroll
  for (int j = 0; j < 10; ++j) pacc[j] = v * Wf2[t * 10 + j];
#pragma unroll
  for (int j = 0; j < 10; ++j)
#pragma unroll
    for (int d = 32; d > 0; d >>= 1)
      pacc[j] += __shfl_down(pacc[j], d);
  int wv = t >> 6, ln = t & 63;
  if (ln == 0) {
#pragma unroll
    for (int j = 0; j < 10; ++j) red[wv][j] = pacc[j];
  }
  __syncthreads();
  if (t == 0) {
    float lg[10];
    float m = -1e30f;
#pragma unroll
    for (int j = 0; j < 10; ++j) {
      float z = bf2[j];
#pragma unroll
      for (int wq = 0; wq < 8; ++wq) z += red[wq][j];
      lg[j] = z;
      m = fmaxf(m, z);
    }
    float sum = 0.f;
#pragma unroll
    for (int j = 0; j < 10; ++j) { lg[j] = __expf(lg[j] - m); sum += lg[j]; }
    float inv = 1.f / sum;
#pragma unroll
    for (int j = 0; j < 10; ++j) out[b * 10 + j] = lg[j] * inv;
  }
}

extern "C" void kernel_launch(void* const* d_in, const int* in_sizes, int n_in,
                              void* d_out, int out_size, void* d_ws, size_t ws_size,
                              hipStream_t stream) {
  const float* x    = (const float*)d_in[0];
  const int*   erow = (const int*)d_in[1];
  const int*   ecol = (const int*)d_in[2];
  const float* ev   = (const float*)d_in[3];
  const float* W1   = (const float*)d_in[4];
  const float* b1   = (const float*)d_in[5];
  const float* W2   = (const float*)d_in[6];
  const float* b2   = (const float*)d_in[7];
  const float* Wf1  = (const float*)d_in[8];
  const float* bf1  = (const float*)d_in[9];
  const float* Wf2  = (const float*)d_in[10];
  const float* bf2  = (const float*)d_in[11];
  float* out = (float*)d_out;

  const size_t partial_bytes = (size_t)S_SPLIT * 256 * 512 * 4;   // 29,360,128
  const size_t flat_bytes    = (size_t)B_ * NK * 2;               // 12,845,056
  const size_t wf1t_bytes    = (size_t)H_ * NK * 2;               // 25,690,112

  // ws layout (~68 MB):
  //   [0, 0.80M)           xT f32            (dead after gc1)
  //   [0.80M, 1.61M)       agg1 f32          (dead after gc2)
  //   [0, 29.36M)          partial           (fc1 writes after xT/agg1 dead)
  //   [29.36M, 42.21M)     flat bf16
  //   [42.21M, 67.90M)     wf1t bf16 (Wf1 transposed)
  //   tail                 CSR (row_ptr, col_s, val_s)
  char* ws = (char*)d_ws;
  float* partial = (float*)ws;
  float* xT   = (float*)ws;
  float* agg1 = (float*)(ws + 802816);
  __hip_bfloat16* flat = (__hip_bfloat16*)(ws + partial_bytes);
  __hip_bfloat16* wf1t = (__hip_bfloat16*)(ws + partial_bytes + flat_bytes);
  char* tail = ws + partial_bytes + flat_bytes + wf1t_bytes;
  int*   row_ptr = (int*)tail;
  int*   col_s   = (int*)(tail + 3152);
  float* val_s   = (float*)(tail + 3152 + E_ * 4);

  hipLaunchKernelGGL(k_prep, dim3(1 + 200), dim3(1024), 0, stream,
                     erow, ecol, ev, x, row_ptr, col_s, val_s, xT);
  hipLaunchKernelGGL(k_gc1, dim3(N_ + 196 * 8), dim3(256), 0, stream,
                     xT, row_ptr, col_s, val_s, Wf1, wf1t, agg1);
  hipLaunchKernelGGL(k_gc2, dim3(N_ * 4 + 392 * 16), dim3(64), 0, stream,
                     agg1, row_ptr, col_s, val_s, W1, b1, W2, b2, Wf1, wf1t, flat);
  hipLaunchKernelGGL(k_fc1, dim3(448), dim3(512), 0, stream,
                     flat, wf1t, partial);
  hipLaunchKernelGGL(k_head, dim3(B_), dim3(512), 0, stream,
                     partial, bf1, Wf2, bf2, out);
}

// Round 26
// 79.905 us; speedup vs baseline: 1.0248x; 1.0248x over previous
//
#include <hip/hip_runtime.h>
#include <hip/hip_bf16.h>

#define B_ 256
#define N_ 784
#define E_ 6272
#define C_ 32
#define H_ 512
#define NK 25088            // N_*C_  (K of fc1; wf1t row stride)
#define S_SPLIT 28

typedef __attribute__((ext_vector_type(8))) short short8;
typedef __attribute__((ext_vector_type(4))) float f32x4;

__device__ __forceinline__ float elu1(float v) {
  return v > 0.f ? v : (__expf(v) - 1.f);
}

__device__ __forceinline__ unsigned short bf16b(float v) {
  __hip_bfloat16 h = __float2bfloat16(v);
  return *reinterpret_cast<unsigned short*>(&h);
}

__device__ __forceinline__ unsigned int pk2(float lo, float hi) {
  return (unsigned int)bf16b(lo) | ((unsigned int)bf16b(hi) << 16);
}

// ---- K0: block 0 = CSR; blocks 1..200 = x transpose ----
__global__ __launch_bounds__(1024) void k_prep(
    const int* __restrict__ erow, const int* __restrict__ ecol,
    const float* __restrict__ eval, const float* __restrict__ x,
    int* __restrict__ row_ptr, int* __restrict__ col_s, float* __restrict__ val_s,
    float* __restrict__ xT) {
  const int t = threadIdx.x;
  if (blockIdx.x == 0) {
    __shared__ int cnt[N_];
    __shared__ int off[N_];
    __shared__ int bufA[1024];
    __shared__ int bufB[1024];
    if (t < N_) cnt[t] = 0;
    __syncthreads();
    for (int e = t; e < E_; e += 1024) atomicAdd(&cnt[erow[e]], 1);
    __syncthreads();
    bufA[t] = (t < N_) ? cnt[t] : 0;
    __syncthreads();
    int* src = bufA; int* dst = bufB;
    for (int d = 1; d < 1024; d <<= 1) {
      int v = src[t];
      if (t >= d) v += src[t - d];
      dst[t] = v;
      __syncthreads();
      int* tmp = src; src = dst; dst = tmp;
    }
    if (t < N_) {
      int ex = src[t] - cnt[t];
      off[t] = ex;
      row_ptr[t] = ex;
    }
    if (t == 0) row_ptr[N_] = E_;
    __syncthreads();
    for (int e = t; e < E_; e += 1024) {
      int r = erow[e];
      int p = atomicAdd(&off[r], 1);
      col_s[p] = ecol[e];
      val_s[p] = eval[e];
    }
  } else {
    __shared__ float tile[32][33];
    int bid = blockIdx.x - 1;
    int n0 = (bid % 25) * 32, b0 = (bid / 25) * 32;
    int ni = t & 31, bi = t >> 5;
    int n = n0 + ni;
    if (n < N_) tile[ni][bi] = x[(b0 + bi) * N_ + n];
    __syncthreads();
    int nj = t >> 5, bj = t & 31;
    int nw = n0 + nj;
    if (nw < N_) xT[nw * B_ + b0 + bj] = tile[nj][bj];
  }
}

// ---- K1: blocks [0,784): spmm1 -> agg1[n][b] (f32 scalar per node)
//      blocks [784,2352): Wf1 cvt+T part1 (k in [0,12544), 64x64 tiles) ----
__global__ __launch_bounds__(256) void k_gc1(
    const float* __restrict__ xT, const int* __restrict__ row_ptr,
    const int* __restrict__ col_s, const float* __restrict__ val_s,
    const float* __restrict__ Wf1, __hip_bfloat16* __restrict__ wf1t,
    float* __restrict__ agg1) {
  __shared__ union {
    struct { int lc[64]; float lv[64]; } g;
    float tile[64][65];
  } sm;
  int t = threadIdx.x;
  if (blockIdx.x < N_) {
    int n = blockIdx.x;
    int e0 = row_ptr[n], deg = row_ptr[n + 1] - e0;
    float agg = 0.f;
    for (int base = 0; base < deg; base += 64) {
      int m = min(64, deg - base);
      __syncthreads();
      if (t < m) { sm.g.lc[t] = col_s[e0 + base + t]; sm.g.lv[t] = val_s[e0 + base + t]; }
      __syncthreads();
      int e = 0;
      for (; e + 4 <= m; e += 4) {
        float x0 = xT[sm.g.lc[e + 0] * B_ + t];
        float x1 = xT[sm.g.lc[e + 1] * B_ + t];
        float x2 = xT[sm.g.lc[e + 2] * B_ + t];
        float x3 = xT[sm.g.lc[e + 3] * B_ + t];
        agg = fmaf(sm.g.lv[e + 0], x0, agg);
        agg = fmaf(sm.g.lv[e + 1], x1, agg);
        agg = fmaf(sm.g.lv[e + 2], x2, agg);
        agg = fmaf(sm.g.lv[e + 3], x3, agg);
      }
      for (; e < m; ++e)
        agg = fmaf(sm.g.lv[e], xT[sm.g.lc[e] * B_ + t], agg);
    }
    agg1[n * B_ + t] = agg;
  } else {
    // Wf1 transpose part1: 196 k-tiles x 8 n-tiles of 64x64, k0 in [0, 12544)
    int bid = blockIdx.x - N_;                 // 0..1567
    int k0 = (bid % 196) * 64, n0 = (bid / 196) * 64;
#pragma unroll
    for (int it = 0; it < 16; ++it) {
      int idx = it * 256 + t;
      int kk = idx >> 6, nn = idx & 63;
      sm.tile[kk][nn] = Wf1[(size_t)(k0 + kk) * H_ + n0 + nn];
    }
    __syncthreads();
#pragma unroll
    for (int it = 0; it < 8; ++it) {
      int idx = it * 256 + t;
      int nn = idx >> 5, kp = idx & 31;
      unsigned int v = pk2(sm.tile[2 * kp][nn], sm.tile[2 * kp + 1][nn]);
      *reinterpret_cast<unsigned int*>(
          wf1t + (size_t)(n0 + nn) * NK + k0 + 2 * kp) = v;
    }
  }
}

// ---- K2: blocks [0,3136): spmm2 via SCALAR gather + in-register h recompute
//      blocks [3136,9408): Wf1 cvt+T part2 (k in [12544,25088), 32x32 tiles) ----
__global__ __launch_bounds__(64) void k_gc2(
    const float* __restrict__ agg1, const int* __restrict__ row_ptr,
    const int* __restrict__ col_s, const float* __restrict__ val_s,
    const float* __restrict__ W1, const float* __restrict__ b1,
    const float* __restrict__ W2, const float* __restrict__ b2,
    const float* __restrict__ Wf1, __hip_bfloat16* __restrict__ wf1t,
    __hip_bfloat16* __restrict__ flat) {
  __shared__ union {
    struct { int lc[64]; float lv[64]; } g;
    float tile[32][33];
  } sm;
  int bid = blockIdx.x;
  int t = threadIdx.x;
  if (bid < N_ * 4) {
    int q = bid & 3;
    int n = bid >> 2;
    int tb = q * 64 + t;
    int e0 = row_ptr[n], deg = row_ptr[n + 1] - e0;
    float w1r[C_], b1r[C_];
#pragma unroll
    for (int c = 0; c < C_; ++c) { w1r[c] = W1[c]; b1r[c] = b1[c]; }
    float acc[C_];
#pragma unroll
    for (int c = 0; c < C_; ++c) acc[c] = 0.f;
    for (int base = 0; base < deg; base += 64) {
      int m = min(64, deg - base);
      __syncthreads();
      if (t < m) { sm.g.lc[t] = col_s[e0 + base + t]; sm.g.lv[t] = val_s[e0 + base + t]; }
      __syncthreads();
      int e = 0;
      for (; e + 4 <= m; e += 4) {
        float s0 = agg1[sm.g.lc[e + 0] * B_ + tb];
        float s1 = agg1[sm.g.lc[e + 1] * B_ + tb];
        float s2 = agg1[sm.g.lc[e + 2] * B_ + tb];
        float s3 = agg1[sm.g.lc[e + 3] * B_ + tb];
        float v0 = sm.g.lv[e + 0], v1 = sm.g.lv[e + 1];
        float v2 = sm.g.lv[e + 2], v3 = sm.g.lv[e + 3];
#pragma unroll
        for (int c = 0; c < C_; ++c) {
          acc[c] = fmaf(v0, elu1(fmaf(s0, w1r[c], b1r[c])), acc[c]);
          acc[c] = fmaf(v1, elu1(fmaf(s1, w1r[c], b1r[c])), acc[c]);
          acc[c] = fmaf(v2, elu1(fmaf(s2, w1r[c], b1r[c])), acc[c]);
          acc[c] = fmaf(v3, elu1(fmaf(s3, w1r[c], b1r[c])), acc[c]);
        }
      }
      for (; e < m; ++e) {
        float s0 = agg1[sm.g.lc[e] * B_ + tb];
        float v0 = sm.g.lv[e];
#pragma unroll
        for (int c = 0; c < C_; ++c)
          acc[c] = fmaf(v0, elu1(fmaf(s0, w1r[c], b1r[c])), acc[c]);
      }
    }
    union { unsigned int u[16]; uint4 v[4]; } ob;
#pragma unroll
    for (int c2 = 0; c2 < C_; c2 += 2) {
      float o0 = b2[c2], o1 = b2[c2 + 1];
#pragma unroll
      for (int c = 0; c < C_; ++c) {
        o0 = fmaf(acc[c], W2[c * C_ + c2], o0);
        o1 = fmaf(acc[c], W2[c * C_ + c2 + 1], o1);
      }
      ob.u[c2 >> 1] = pk2(elu1(o0), elu1(o1));
    }
    uint4* dst = reinterpret_cast<uint4*>(flat + (size_t)tb * NK + n * C_);
#pragma unroll
    for (int j = 0; j < 4; ++j) dst[j] = ob.v[j];
  } else {
    // Wf1 transpose part2: 392 k-tiles x 16 n-tiles of 32x32, k0 in [12544, NK)
    int bid2 = bid - N_ * 4;                   // 0..6271
    int k0 = 12544 + (bid2 % 392) * 32, n0 = (bid2 / 392) * 32;
#pragma unroll
    for (int it = 0; it < 16; ++it) {
      int idx = it * 64 + t;
      int kk = idx >> 5, nn = idx & 31;
      sm.tile[kk][nn] = Wf1[(size_t)(k0 + kk) * H_ + n0 + nn];
    }
    __syncthreads();
#pragma unroll
    for (int it = 0; it < 8; ++it) {
      int idx = it * 64 + t;
      int nn = idx >> 4, kp = idx & 15;
      unsigned int v = pk2(sm.tile[2 * kp][nn], sm.tile[2 * kp + 1][nn]);
      *reinterpret_cast<unsigned int*>(
          wf1t + (size_t)(n0 + nn) * NK + k0 + 2 * kp) = v;
    }
  }
}

// ---- K3: fc1 split-K MFMA GEMM, BM=128 x BN=128, 8 waves, 3-buffer pipeline ----
// (round-24 verified best: grid 224 XCD-swizzled, VWAIT(4), 96KB LDS)
__global__ __launch_bounds__(512, 1) void k_fc1(
    const __hip_bfloat16* __restrict__ flat, const __hip_bfloat16* __restrict__ wf1t,
    float* __restrict__ partial) {
  __shared__ unsigned char lds[3 * 32768];
  int raw = blockIdx.x;
  int bid = (raw & 7) * 28 + (raw >> 3);      // bijective XCD swizzle (224 = 8*28)
  int s = bid >> 3, r8 = bid & 7;
  int m0 = (r8 & 1) * 128;
  int n0 = (r8 >> 1) * 128;
  int k0 = s * 896;
  int tid = threadIdx.x;
  int w = tid >> 6, l = tid & 63;
  int r = l & 15, g = l >> 4;

  const __hip_bfloat16* src[4];
  int ldsoff[4];
#pragma unroll
  for (int j = 0; j < 4; ++j) {
    int reg = w * 4 + j;
    ldsoff[j] = reg * 1024 + l * 16;
    if (reg < 16) {
      int fmg = reg >> 1, ks = reg & 1;
      src[j] = flat + (size_t)(m0 + fmg * 16 + r) * NK + (k0 + ks * 32 + g * 8);
    } else {
      int fng = (reg - 16) >> 1, ks = reg & 1;
      src[j] = wf1t + (size_t)(n0 + fng * 16 + r) * NK + (k0 + ks * 32 + g * 8);
    }
  }

  f32x4 acc[4][2];
#pragma unroll
  for (int i = 0; i < 4; ++i)
#pragma unroll
    for (int j = 0; j < 2; ++j) acc[i][j] = (f32x4){0.f, 0.f, 0.f, 0.f};

#define GLOAD_LDS(gp, lp)                                                     \
  __builtin_amdgcn_global_load_lds(                                           \
      (const __attribute__((address_space(1))) unsigned int*)(gp),            \
      (__attribute__((address_space(3))) unsigned int*)(lp), 16, 0, 0)
#define STAGE(t, buf) do {                                                    \
    _Pragma("unroll")                                                         \
    for (int j = 0; j < 4; ++j)                                               \
      GLOAD_LDS(src[j] + (t) * 64, &lds[(buf) * 32768 + ldsoff[j]]);          \
  } while (0)
#define VWAIT(n) do {                                                         \
    asm volatile("s_waitcnt vmcnt(%0)" :: "n"(n) : "memory");                 \
    __builtin_amdgcn_sched_barrier(0);                                        \
  } while (0)
#define BAR() do {                                                            \
    __builtin_amdgcn_s_barrier();                                             \
    __builtin_amdgcn_sched_barrier(0);                                        \
  } while (0)
#define COMPUTE(buf) do {                                                     \
    const unsigned char* bb = &lds[(buf) * 32768];                            \
    short8 af[4][2], bf[2][2];                                                \
    _Pragma("unroll")                                                         \
    for (int fm = 0; fm < 4; ++fm)                                            \
      _Pragma("unroll")                                                       \
      for (int ks = 0; ks < 2; ++ks)                                          \
        af[fm][ks] = *reinterpret_cast<const short8*>(                        \
            bb + ((((w & 1) * 4 + fm) * 2 + ks) << 10) + l * 16);             \
    _Pragma("unroll")                                                         \
    for (int fn = 0; fn < 2; ++fn)                                            \
      _Pragma("unroll")                                                       \
      for (int ks = 0; ks < 2; ++ks)                                          \
        bf[fn][ks] = *reinterpret_cast<const short8*>(                        \
            bb + ((16 + ((w >> 1) * 2 + fn) * 2 + ks) << 10) + l * 16);       \
    _Pragma("unroll")                                                         \
    for (int ks = 0; ks < 2; ++ks)                                            \
      _Pragma("unroll")                                                       \
      for (int fn = 0; fn < 2; ++fn)                                          \
        _Pragma("unroll")                                                     \
        for (int fm = 0; fm < 4; ++fm)                                        \
          acc[fm][fn] = __builtin_amdgcn_mfma_f32_16x16x32_bf16(              \
              af[fm][ks], bf[fn][ks], acc[fm][fn], 0, 0, 0);                  \
  } while (0)
#define STEP(t) do {                                                          \
    VWAIT((t) < 13 ? 4 : 0);                                                  \
    BAR();                                                                    \
    if ((t) + 2 <= 13) STAGE((t) + 2, ((t) + 2) % 3);                         \
    COMPUTE((t) % 3);                                                         \
  } while (0)

  STAGE(0, 0);
  STAGE(1, 1);
  STEP(0);  STEP(1);  STEP(2);  STEP(3);  STEP(4);  STEP(5);  STEP(6);
  STEP(7);  STEP(8);  STEP(9);  STEP(10); STEP(11); STEP(12); STEP(13);

#undef GLOAD_LDS
#undef STAGE
#undef VWAIT
#undef BAR
#undef COMPUTE
#undef STEP

  int wm = (w & 1) * 64, wn = (w >> 1) * 32;
  float* p = partial + (size_t)s * (256 * 512);
#pragma unroll
  for (int fm = 0; fm < 4; ++fm)
#pragma unroll
    for (int fn = 0; fn < 2; ++fn)
#pragma unroll
      for (int q = 0; q < 4; ++q) {
        int m = m0 + wm + fm * 16 + g * 4 + q;
        int n = n0 + wn + fn * 16 + r;
        p[m * 512 + n] = acc[fm][fn][q];
      }
}

// ---------------- K4: reduce partials + bias + relu + fc2 + softmax ----------------
__global__ __launch_bounds__(512) void k_head(
    const float* __restrict__ partial, const float* __restrict__ bf1,
    const float* __restrict__ Wf2, const float* __restrict__ bf2,
    float* __restrict__ out) {
  __shared__ float red[8][12];
  int b = blockIdx.x;
  int t = threadIdx.x;
  float v = bf1[t];
#pragma unroll
  for (int s = 0; s < S_SPLIT; ++s)
    v += partial[(size_t)s * (256 * 512) + b * 512 + t];
  v = fmaxf(v, 0.f);
  float pacc[10];
#pragma unroll
  for (int j = 0; j < 10; ++j) pacc[j] = v * Wf2[t * 10 + j];
#pragma unroll
  for (int j = 0; j < 10; ++j)
#pragma unroll
    for (int d = 32; d > 0; d >>= 1)
      pacc[j] += __shfl_down(pacc[j], d);
  int wv = t >> 6, ln = t & 63;
  if (ln == 0) {
#pragma unroll
    for (int j = 0; j < 10; ++j) red[wv][j] = pacc[j];
  }
  __syncthreads();
  if (t == 0) {
    float lg[10];
    float m = -1e30f;
#pragma unroll
    for (int j = 0; j < 10; ++j) {
      float z = bf2[j];
#pragma unroll
      for (int wq = 0; wq < 8; ++wq) z += red[wq][j];
      lg[j] = z;
      m = fmaxf(m, z);
    }
    float sum = 0.f;
#pragma unroll
    for (int j = 0; j < 10; ++j) { lg[j] = __expf(lg[j] - m); sum += lg[j]; }
    float inv = 1.f / sum;
#pragma unroll
    for (int j = 0; j < 10; ++j) out[b * 10 + j] = lg[j] * inv;
  }
}

extern "C" void kernel_launch(void* const* d_in, const int* in_sizes, int n_in,
                              void* d_out, int out_size, void* d_ws, size_t ws_size,
                              hipStream_t stream) {
  const float* x    = (const float*)d_in[0];
  const int*   erow = (const int*)d_in[1];
  const int*   ecol = (const int*)d_in[2];
  const float* ev   = (const float*)d_in[3];
  const float* W1   = (const float*)d_in[4];
  const float* b1   = (const float*)d_in[5];
  const float* W2   = (const float*)d_in[6];
  const float* b2   = (const float*)d_in[7];
  const float* Wf1  = (const float*)d_in[8];
  const float* bf1  = (const float*)d_in[9];
  const float* Wf2  = (const float*)d_in[10];
  const float* bf2  = (const float*)d_in[11];
  float* out = (float*)d_out;

  const size_t partial_bytes = (size_t)S_SPLIT * 256 * 512 * 4;   // 14,680,064
  const size_t flat_bytes    = (size_t)B_ * NK * 2;               // 12,845,056
  const size_t wf1t_bytes    = (size_t)H_ * NK * 2;               // 25,690,112

  // ws layout (~53.3 MB):
  //   [0, 0.80M)           xT f32            (dead after gc1)
  //   [0.80M, 1.61M)       agg1 f32          (dead after gc2)
  //   [0, 14.68M)          partial           (fc1 writes after xT/agg1 dead)
  //   [14.68M, 27.53M)     flat bf16
  //   [27.53M, 53.22M)     wf1t bf16 (Wf1 transposed)
  //   tail                 CSR (row_ptr, col_s, val_s)
  char* ws = (char*)d_ws;
  float* partial = (float*)ws;
  float* xT   = (float*)ws;
  float* agg1 = (float*)(ws + 802816);
  __hip_bfloat16* flat = (__hip_bfloat16*)(ws + partial_bytes);
  __hip_bfloat16* wf1t = (__hip_bfloat16*)(ws + partial_bytes + flat_bytes);
  char* tail = ws + partial_bytes + flat_bytes + wf1t_bytes;
  int*   row_ptr = (int*)tail;
  int*   col_s   = (int*)(tail + 3152);
  float* val_s   = (float*)(tail + 3152 + E_ * 4);

  hipLaunchKernelGGL(k_prep, dim3(1 + 200), dim3(1024), 0, stream,
                     erow, ecol, ev, x, row_ptr, col_s, val_s, xT);
  hipLaunchKernelGGL(k_gc1, dim3(N_ + 196 * 8), dim3(256), 0, stream,
                     xT, row_ptr, col_s, val_s, Wf1, wf1t, agg1);
  hipLaunchKernelGGL(k_gc2, dim3(N_ * 4 + 392 * 16), dim3(64), 0, stream,
                     agg1, row_ptr, col_s, val_s, W1, b1, W2, b2, Wf1, wf1t, flat);
  hipLaunchKernelGGL(k_fc1, dim3(224), dim3(512), 0, stream,
                     flat, wf1t, partial);
  hipLaunchKernelGGL(k_head, dim3(B_), dim3(512), 0, stream,
                     partial, bf1, Wf2, bf2, out);
}